// Round 7
// baseline (766.379 us; speedup 1.0000x reference)
//
#include <hip/hip_runtime.h>
#include <cstdint>
#include <cstddef>

#define D 2048
#define L 8
#define KT 4096            // stacked K (pos|neg)
#define BM 256
#define BN 128
#define BK 32
#define NT (KT / BK)       // 128 K-tiles
#define BUFSZ ((BM + BN) * BK)   // 12288 f16 = 24 KiB per LDS buffer

typedef _Float16 f16;
typedef _Float16 f16x4 __attribute__((ext_vector_type(4)));
typedef _Float16 f16x8 __attribute__((ext_vector_type(8)));
typedef float f32x4 __attribute__((ext_vector_type(4)));

__device__ __forceinline__ void gload16(const void* g, void* l) {
  __builtin_amdgcn_global_load_lds(
      (const __attribute__((address_space(1))) void*)g,
      (__attribute__((address_space(3))) void*)l, 16, 0, 0);
}

// ---- init: A -> Abig = [[A+|A-];[A-|A+]], bias init + step-0 contribution --
__global__ __launch_bounds__(256) void k_init(
    const float* __restrict__ A, const float* __restrict__ b,
    const float* __restrict__ db1, const float* __restrict__ db2,  // layer 7
    f16* __restrict__ Ab, float* __restrict__ blbu, float* __restrict__ outacc) {
  const int m = blockIdx.x, tid = threadIdx.x;
  if (m < 2) {
    f32x4 z = {0.f, 0.f, 0.f, 0.f};
    *(f32x4*)(outacc + m * 2048 + tid * 8) = z;
    *(f32x4*)(outacc + m * 2048 + tid * 8 + 4) = z;
  }
  const int k = tid * 8;
  size_t i = (size_t)m * D + k;
  f32x4 a0 = *(const f32x4*)(A + i);
  f32x4 a1 = *(const f32x4*)(A + i + 4);
  f16x8 p, n;
  float cL = 0.f, cU = 0.f;
#pragma unroll
  for (int j = 0; j < 8; ++j) {
    float v = (j < 4) ? a0[j] : a1[j - 4];
    float pf = fmaxf(v, 0.f), nf = fminf(v, 0.f);
    p[j] = (f16)pf; n[j] = (f16)nf;
    float w1 = db1[k + j], w2 = db2[k + j];
    cL += pf * w1 + nf * w2;
    cU += pf * w2 + nf * w1;
  }
  size_t lo = (size_t)m * KT + k;
  size_t hi = (size_t)(D + m) * KT + k;
  *(f16x8*)(Ab + lo) = p;      *(f16x8*)(Ab + lo + D) = n;
  *(f16x8*)(Ab + hi) = n;      *(f16x8*)(Ab + hi + D) = p;

  __shared__ float redL[4], redU[4];
#pragma unroll
  for (int off = 32; off > 0; off >>= 1) {
    cL += __shfl_down(cL, off);
    cU += __shfl_down(cU, off);
  }
  const int wave = tid >> 6, lane = tid & 63;
  if (lane == 0) { redL[wave] = cL; redU[wave] = cU; }
  __syncthreads();
  if (tid == 0) {
    float bL = b[m] + redL[0] + redL[1] + redL[2] + redL[3];
    float bU = b[m] + redU[0] + redU[1] + redU[2] + redU[3];
    blbu[m] = bL; blbu[D + m] = bU;
  }
}

// ---- LDS-free transpose panel (512 thr): Bb[n][koff+k] = (f16)src[k][n] ----
// blk in [0,2048): 1024 blocks per matrix; block covers 64 cols x 64 k
__device__ __forceinline__ void transpose_panel(
    const float* __restrict__ srcAl, const float* __restrict__ srcAu,
    f16* __restrict__ Bb, int blk, int tid) {
  const int z = blk >> 10;
  const int rem = blk & 1023;
  const float* src = z ? srcAu : srcAl;
  const int koff = z ? D : 0;
  const int nb = (rem & 31) * 64;
  const int kb = (rem >> 5) * 64;
  const int col = nb + (tid & 63);
  const int k0 = kb + (tid >> 6) * 8;
  float v[8];
#pragma unroll
  for (int j = 0; j < 8; ++j)
    v[j] = src[(size_t)(k0 + j) * D + col];
  f16x8 h;
#pragma unroll
  for (int j = 0; j < 8; ++j) h[j] = (f16)v[j];
  *(f16x8*)(Bb + (size_t)col * KT + koff + k0) = h;
}

__global__ __launch_bounds__(512) void k_prep(
    const float* __restrict__ srcAl, const float* __restrict__ srcAu,
    f16* __restrict__ Bb) {
  transpose_panel(srcAl, srcAu, Bb, blockIdx.x, threadIdx.x);
}

// ---- step GEMM: 8 waves, per-wave 64x64 C, 2-phase/K-tile interleave -------
// BK=32 rows (64 B): logical chunk c of row r stored at phys c^((r>>1)&3);
// gload_lds writes linear, global source pre-swizzled (rule 21). 0 conflicts
// (measured R6). Phase = {ds_reads + staged gloads, barrier, lgkm0,
// setprio 8xMFMA, barrier}; counted vmcnt(3) once per tile (3 loads/tile,
// 2 tiles in flight).
__global__ __launch_bounds__(512, 2) void k_gemm(
    const f16* __restrict__ A,     // [2D][KT] state
    const f16* __restrict__ BT,    // [D][KT] current layer (transposed)
    f16* __restrict__ BTn,         // next layer's B buffer (backfill target)
    const float* __restrict__ nAl, const float* __restrict__ nAu,
    const float* __restrict__ w1, const float* __restrict__ w2,
    float* __restrict__ bdst,      // blbu (t<7) or outacc (t=7)
    f16* __restrict__ An) {        // [2D][KT] next state
  __shared__ __align__(16) f16 lds[3 * BUFSZ];   // 72 KiB tri-buffer

  if (blockIdx.x >= 256) {   // backfill: transpose next layer (co-resident)
    transpose_panel(nAl, nAu, BTn, blockIdx.x - 256, threadIdx.x);
    return;
  }

  // bijective XCD swizzle over the 16x16 tile grid
  const int flat = blockIdx.x;
  const int xcd = flat & 7, idx = flat >> 3;
  const int by = (xcd >> 1) * 4 + (idx >> 3);
  const int bx = (xcd & 1) * 8 + (idx & 7);
  const int m0 = by * BM;
  const int n0 = bx * BN;

  const int tid = threadIdx.x;
  const int wave = tid >> 6, lane = tid & 63;
  const int wm = (wave & 3) * 64, wn = (wave >> 2) * 64;
  const int lr = lane & 15, lq = lane >> 4;
  const int srow = lane >> 2;                        // staging row in 16-row chunk
  const int scol = ((lane & 3) ^ ((lane >> 3) & 3)) * 8;  // pre-swizzled src chunk
  const int rchunk = (lq ^ ((lr >> 1) & 3)) * 8;     // swizzled read chunk (f16)

  f32x4 acc[4][4];
#pragma unroll
  for (int m = 0; m < 4; ++m)
#pragma unroll
    for (int n = 0; n < 4; ++n)
      acc[m][n] = (f32x4){0.f, 0.f, 0.f, 0.f};

  // staging: A = 16 chunks of 16 rows (r = i*8+wave, i 0..1), B = 8 chunks
  auto stageA = [&](size_t gk, f16* sA, int i) {
    const int r = i * 8 + wave;
    gload16(A + (size_t)(m0 + r * 16 + srow) * KT + gk + scol, sA + r * 512);
  };
  auto stageB = [&](size_t gk, f16* sB) {
    gload16(BT + (size_t)(n0 + wave * 16 + srow) * KT + gk + scol,
            sB + wave * 512);
  };
  auto lda = [&](const f16* bA, int m) {
    return *(const f16x8*)(bA + (wm + m * 16 + lr) * BK + rchunk);
  };
  auto ldb = [&](const f16* bB, int n) {
    return *(const f16x8*)(bB + (wn + n * 16 + lr) * BK + rchunk);
  };

#define SYNC_PRE()  do { __builtin_amdgcn_sched_barrier(0);                 \
    __builtin_amdgcn_s_barrier();                                           \
    asm volatile("s_waitcnt lgkmcnt(0)" ::: "memory");                      \
    __builtin_amdgcn_sched_barrier(0); } while (0)
#define SYNC_POST() do { __builtin_amdgcn_sched_barrier(0);                 \
    __builtin_amdgcn_s_barrier(); } while (0)

  // prologue: 2 tiles in flight, wait for the first (3 loads/tile)
  { f16* s0 = lds;            f16* s0b = s0 + BM * BK;
    f16* s1 = lds + BUFSZ;    f16* s1b = s1 + BM * BK;
    stageA(0, s0, 0); stageA(0, s0, 1); stageB(0, s0b);
    stageA(BK, s1, 0); stageA(BK, s1, 1); stageB(BK, s1b);
  }
  asm volatile("s_waitcnt vmcnt(3)" ::: "memory");
  __builtin_amdgcn_sched_barrier(0);
  __builtin_amdgcn_s_barrier();
  __builtin_amdgcn_sched_barrier(0);

  for (int t = 0; t < NT; ++t) {
    const f16* bA = lds + (t % 3) * BUFSZ;
    const f16* bB = bA + BM * BK;
    f16* sA = lds + ((t + 2) % 3) * BUFSZ;
    f16* sB = sA + BM * BK;
    const bool pf = (t + 2 < NT);
    const size_t gk = (size_t)(t + 2) * BK;

    // ---- phase 0: B frags + low A frags, stage 2 A-gloads, MFMA m=0,1 ----
    f16x8 b0 = ldb(bB, 0), b1 = ldb(bB, 1), b2 = ldb(bB, 2), b3 = ldb(bB, 3);
    f16x8 a0 = lda(bA, 0), a1 = lda(bA, 1);
    if (pf) { stageA(gk, sA, 0); stageA(gk, sA, 1); }
    SYNC_PRE();
    __builtin_amdgcn_s_setprio(1);
    acc[0][0] = __builtin_amdgcn_mfma_f32_16x16x32_f16(b0, a0, acc[0][0], 0, 0, 0);
    acc[0][1] = __builtin_amdgcn_mfma_f32_16x16x32_f16(b1, a0, acc[0][1], 0, 0, 0);
    acc[0][2] = __builtin_amdgcn_mfma_f32_16x16x32_f16(b2, a0, acc[0][2], 0, 0, 0);
    acc[0][3] = __builtin_amdgcn_mfma_f32_16x16x32_f16(b3, a0, acc[0][3], 0, 0, 0);
    acc[1][0] = __builtin_amdgcn_mfma_f32_16x16x32_f16(b0, a1, acc[1][0], 0, 0, 0);
    acc[1][1] = __builtin_amdgcn_mfma_f32_16x16x32_f16(b1, a1, acc[1][1], 0, 0, 0);
    acc[1][2] = __builtin_amdgcn_mfma_f32_16x16x32_f16(b2, a1, acc[1][2], 0, 0, 0);
    acc[1][3] = __builtin_amdgcn_mfma_f32_16x16x32_f16(b3, a1, acc[1][3], 0, 0, 0);
    __builtin_amdgcn_s_setprio(0);
    SYNC_POST();

    // ---- phase 1: high A frags, stage 1 B-gload, counted vmcnt, MFMA m=2,3
    f16x8 a2 = lda(bA, 2), a3 = lda(bA, 3);
    if (pf) {
      stageB(gk, sB);
      asm volatile("s_waitcnt vmcnt(3)" ::: "memory");
    } else if (t + 1 < NT) {
      asm volatile("s_waitcnt vmcnt(0)" ::: "memory");
    }
    SYNC_PRE();
    __builtin_amdgcn_s_setprio(1);
    acc[2][0] = __builtin_amdgcn_mfma_f32_16x16x32_f16(b0, a2, acc[2][0], 0, 0, 0);
    acc[2][1] = __builtin_amdgcn_mfma_f32_16x16x32_f16(b1, a2, acc[2][1], 0, 0, 0);
    acc[2][2] = __builtin_amdgcn_mfma_f32_16x16x32_f16(b2, a2, acc[2][2], 0, 0, 0);
    acc[2][3] = __builtin_amdgcn_mfma_f32_16x16x32_f16(b3, a2, acc[2][3], 0, 0, 0);
    acc[3][0] = __builtin_amdgcn_mfma_f32_16x16x32_f16(b0, a3, acc[3][0], 0, 0, 0);
    acc[3][1] = __builtin_amdgcn_mfma_f32_16x16x32_f16(b1, a3, acc[3][1], 0, 0, 0);
    acc[3][2] = __builtin_amdgcn_mfma_f32_16x16x32_f16(b2, a3, acc[3][2], 0, 0, 0);
    acc[3][3] = __builtin_amdgcn_mfma_f32_16x16x32_f16(b3, a3, acc[3][3], 0, 0, 0);
    __builtin_amdgcn_s_setprio(0);
    SYNC_POST();
  }

  // ---- epilogue: sign-split store + fused bias contribution ----
  const int low = (m0 < D) ? 1 : 0;
  f32x4 w1v[4], w2v[4];
#pragma unroll
  for (int n = 0; n < 4; ++n) {
    const int col = n0 + wn + n * 16 + lq * 4;
    w1v[n] = *(const f32x4*)(w1 + col);
    w2v[n] = *(const f32x4*)(w2 + col);
  }
  float rowsum[4] = {0.f, 0.f, 0.f, 0.f};
#pragma unroll
  for (int m = 0; m < 4; ++m) {
#pragma unroll
    for (int n = 0; n < 4; ++n) {
      const size_t row = (size_t)(m0 + wm + m * 16 + lr);
      const int col = n0 + wn + n * 16 + lq * 4;
      f16x4 p, q;
#pragma unroll
      for (int r = 0; r < 4; ++r) {
        float v = acc[m][n][r];
        float pf2 = fmaxf(v, 0.f), qf = fminf(v, 0.f);
        p[r] = (f16)pf2;
        q[r] = (f16)qf;
        float wa = low ? w1v[n][r] : w2v[n][r];
        float wb = low ? w2v[n][r] : w1v[n][r];
        rowsum[m] += pf2 * wa + qf * wb;
      }
      f16* base = An + row * KT + col;
      if (low) { *(f16x4*)base = p; *(f16x4*)(base + D) = q; }
      else     { *(f16x4*)base = q; *(f16x4*)(base + D) = p; }
    }
  }
#pragma unroll
  for (int m = 0; m < 4; ++m) {
    float v = rowsum[m];
    v += __shfl_down(v, 32);
    v += __shfl_down(v, 16);
    if (lane < 16)
      atomicAdd(bdst + m0 + wm + m * 16 + lane, v);
  }
}

// ---- final: out[R] = outacc[R] + blbu[R] -----------------------------------
__global__ __launch_bounds__(256) void k_final(
    const float* __restrict__ outacc, const float* __restrict__ blbu,
    float* __restrict__ out) {
  const int R = blockIdx.x * 256 + threadIdx.x;
  out[R] = outacc[R] + blbu[R];
}

// ---- host ------------------------------------------------------------------
extern "C" void kernel_launch(void* const* d_in, const int* in_sizes, int n_in,
                              void* d_out, int out_size, void* d_ws, size_t ws_size,
                              hipStream_t stream) {
  (void)in_sizes; (void)n_in; (void)out_size;
  const float* A   = (const float*)d_in[0];
  const float* b   = (const float*)d_in[1];
  const float* hAl = (const float*)d_in[2];
  const float* hAu = (const float*)d_in[3];
  const float* hbl = (const float*)d_in[4];
  const float* hbu = (const float*)d_in[5];
  const float* lo  = (const float*)d_in[6];
  const float* up  = (const float*)d_in[7];
  float* out = (float*)d_out;

  const size_t AS = (size_t)2 * D * KT;     // Abig elems (f16)
  const size_t BS = (size_t)D * KT;         // Bb elems (f16)
  const size_t MS = (size_t)D * D;
  char* base = (char*)d_ws;
  f16* Ab0   = (f16*)base;
  f16* Ab1   = Ab0 + AS;
  f16* Bb0   = Ab1 + AS;
  float* blbu   = (float*)(Bb0 + BS);
  float* outacc = blbu + 2 * D;
  f16* Bb1   = (f16*)(outacc + 2 * D);
  const size_t need_fused = (size_t)((char*)(Bb1 + BS) - base);
  const bool fused = ws_size >= need_fused;

  k_init<<<dim3(D), 256, 0, stream>>>(
      A, b, hbl + (size_t)7 * D, hbu + (size_t)7 * D, Ab0, blbu, outacc);
  k_prep<<<dim3(2048), 512, 0, stream>>>(          // layer 7 -> Bb0
      hAl + (size_t)7 * MS, hAu + (size_t)7 * MS, Bb0);

  f16* cur = Ab0;
  f16* nxt = Ab1;
  for (int t = 0; t < L; ++t) {
    const int nlayer = 6 - t;   // layer for step t+1 (bias weights + transpose)
    const float* w1 = (t < 7) ? hbl + (size_t)nlayer * D : lo;
    const float* w2 = (t < 7) ? hbu + (size_t)nlayer * D : up;
    float* bd = (t < 7) ? blbu : outacc;
    f16* BT  = (fused && (t & 1)) ? Bb1 : Bb0;
    f16* BTn = fused ? ((t & 1) ? Bb0 : Bb1) : Bb0;
    const float* nl = (t < 7) ? hAl + (size_t)nlayer * MS : hAl;
    const float* nu = (t < 7) ? hAu + (size_t)nlayer * MS : hAu;
    if (!fused && t > 0)
      k_prep<<<dim3(2048), 512, 0, stream>>>(
          hAl + (size_t)(7 - t) * MS, hAu + (size_t)(7 - t) * MS, Bb0);
    const unsigned grid = (fused && t < 7) ? 2304u : 256u;
    k_gemm<<<dim3(grid), 512, 0, stream>>>(cur, BT, BTn, nl, nu, w1, w2, bd, nxt);
    f16* tmp = cur; cur = nxt; nxt = tmp;
  }
  k_final<<<dim3(2 * D / 256), 256, 0, stream>>>(outacc, blbu, out);
}

// Round 8
// 661.022 us; speedup vs baseline: 1.1594x; 1.1594x over previous
//
#include <hip/hip_runtime.h>
#include <cstdint>
#include <cstddef>

#define D 2048
#define L 8
#define KT 4096            // stacked K (pos|neg)
#define BM 256
#define BN 128
#define BK 64
#define NT (KT / BK)       // 64 K-tiles
#define BUFSZ ((BM + BN) * BK)   // 24576 f16 = 48 KiB per LDS buffer

typedef _Float16 f16;
typedef _Float16 f16x4 __attribute__((ext_vector_type(4)));
typedef _Float16 f16x8 __attribute__((ext_vector_type(8)));
typedef float f32x4 __attribute__((ext_vector_type(4)));

__device__ __forceinline__ void gload16(const void* g, void* l) {
  __builtin_amdgcn_global_load_lds(
      (const __attribute__((address_space(1))) void*)g,
      (__attribute__((address_space(3))) void*)l, 16, 0, 0);
}

// ---- init: A -> Abig = [[A+|A-];[A-|A+]], bias init + step-0 contribution --
__global__ __launch_bounds__(256) void k_init(
    const float* __restrict__ A, const float* __restrict__ b,
    const float* __restrict__ db1, const float* __restrict__ db2,  // layer 7
    f16* __restrict__ Ab, float* __restrict__ blbu, float* __restrict__ outacc) {
  const int m = blockIdx.x, tid = threadIdx.x;
  if (m < 2) {
    f32x4 z = {0.f, 0.f, 0.f, 0.f};
    *(f32x4*)(outacc + m * 2048 + tid * 8) = z;
    *(f32x4*)(outacc + m * 2048 + tid * 8 + 4) = z;
  }
  const int k = tid * 8;
  size_t i = (size_t)m * D + k;
  f32x4 a0 = *(const f32x4*)(A + i);
  f32x4 a1 = *(const f32x4*)(A + i + 4);
  f16x8 p, n;
  float cL = 0.f, cU = 0.f;
#pragma unroll
  for (int j = 0; j < 8; ++j) {
    float v = (j < 4) ? a0[j] : a1[j - 4];
    float pf = fmaxf(v, 0.f), nf = fminf(v, 0.f);
    p[j] = (f16)pf; n[j] = (f16)nf;
    float w1 = db1[k + j], w2 = db2[k + j];
    cL += pf * w1 + nf * w2;
    cU += pf * w2 + nf * w1;
  }
  size_t lo = (size_t)m * KT + k;
  size_t hi = (size_t)(D + m) * KT + k;
  *(f16x8*)(Ab + lo) = p;      *(f16x8*)(Ab + lo + D) = n;
  *(f16x8*)(Ab + hi) = n;      *(f16x8*)(Ab + hi + D) = p;

  __shared__ float redL[4], redU[4];
#pragma unroll
  for (int off = 32; off > 0; off >>= 1) {
    cL += __shfl_down(cL, off);
    cU += __shfl_down(cU, off);
  }
  const int wave = tid >> 6, lane = tid & 63;
  if (lane == 0) { redL[wave] = cL; redU[wave] = cU; }
  __syncthreads();
  if (tid == 0) {
    float bL = b[m] + redL[0] + redL[1] + redL[2] + redL[3];
    float bU = b[m] + redU[0] + redU[1] + redU[2] + redU[3];
    blbu[m] = bL; blbu[D + m] = bU;
  }
}

// ---- LDS-free transpose panel (512 thr): Bb[n][koff+k] = (f16)src[k][n] ----
// panel p in [0,2048): 1024 per matrix; covers 64 cols x 64 k
__device__ __forceinline__ void transpose_panel(
    const float* __restrict__ srcAl, const float* __restrict__ srcAu,
    f16* __restrict__ Bb, int p, int tid) {
  const int z = p >> 10;
  const int rem = p & 1023;
  const float* src = z ? srcAu : srcAl;
  const int koff = z ? D : 0;
  const int col = (rem & 31) * 64 + (tid & 63);
  const int k0 = (rem >> 5) * 64 + (tid >> 6) * 8;
  float v[8];
#pragma unroll
  for (int j = 0; j < 8; ++j)
    v[j] = src[(size_t)(k0 + j) * D + col];
  f16x8 h;
#pragma unroll
  for (int j = 0; j < 8; ++j) h[j] = (f16)v[j];
  *(f16x8*)(Bb + (size_t)col * KT + koff + k0) = h;
}

__global__ __launch_bounds__(512) void k_prep(
    const float* __restrict__ srcAl, const float* __restrict__ srcAu,
    f16* __restrict__ Bb) {
  transpose_panel(srcAl, srcAu, Bb, blockIdx.x, threadIdx.x);
}

// ---- step GEMM (R4 structure) + fused bias epilogue + in-loop transpose ----
// Per K-tile: stage(t+2), 2x{8 frag reads, 16 MFMA}, vmcnt(6), barrier.
// Transpose of next layer absorbed: at t==2 (mod 8) issue 8 f32 col-loads
// (older than stage; end-of-tile wait becomes vmcnt(14) so they ride 2 tiles),
// store the f16x8 at t==4 (mod 8). Order pinned with sched_barrier(0).
__global__ __launch_bounds__(512, 2) void k_gemm(
    const f16* __restrict__ A,     // [2D][KT] state
    const f16* __restrict__ BT,    // [D][KT] current layer (transposed)
    f16* __restrict__ BTn,         // next layer's B buffer
    const float* __restrict__ nAl, const float* __restrict__ nAu,
    const float* __restrict__ w1, const float* __restrict__ w2,
    float* __restrict__ bdst,      // blbu (t<7) or outacc (t=7)
    f16* __restrict__ An,          // [2D][KT] next state
    const int do_tr, const int wstate) {
  __shared__ __align__(16) f16 lds[3 * BUFSZ];   // 144 KiB tri-buffer

  // bijective XCD swizzle over the 16x16 tile grid
  const int flat = blockIdx.x;
  const int xcd = flat & 7, idx = flat >> 3;
  const int by = (xcd >> 1) * 4 + (idx >> 3);
  const int bx = (xcd & 1) * 8 + (idx & 7);
  const int m0 = by * BM;
  const int n0 = bx * BN;

  const int tid = threadIdx.x;
  const int wave = tid >> 6, lane = tid & 63;
  const int wm = (wave & 3) * 64, wn = (wave >> 2) * 64;
  const int sub = lane >> 3;                  // row within 8-row region
  const int cg = ((lane & 7) ^ sub) * 8;      // inverse-swizzled src chunk
  const int lr = lane & 15, lq = lane >> 4;

  f32x4 acc[4][4];
#pragma unroll
  for (int m = 0; m < 4; ++m)
#pragma unroll
    for (int n = 0; n < 4; ++n)
      acc[m][n] = (f32x4){0.f, 0.f, 0.f, 0.f};

  auto stage = [&](int kt, int buf) {
    f16* bA = lds + buf * BUFSZ;
    f16* bB = bA + BM * BK;
    const size_t gk = (size_t)kt * BK;
#pragma unroll
    for (int i = 0; i < 4; ++i) {
      const int r = i * 8 + wave;             // 32 regions x 8 rows (A)
      gload16(A + (size_t)(m0 + r * 8 + sub) * KT + gk + cg, bA + r * 512);
    }
#pragma unroll
    for (int i = 0; i < 2; ++i) {
      const int r = i * 8 + wave;             // 16 regions x 8 rows (B)
      gload16(BT + (size_t)(n0 + r * 8 + sub) * KT + gk + cg, bB + r * 512);
    }
  };

  // prologue: 2 tiles in flight, wait for the first
  stage(0, 0);
  stage(1, 1);
  asm volatile("s_waitcnt vmcnt(6)" ::: "memory");
  __builtin_amdgcn_sched_barrier(0);
  __builtin_amdgcn_s_barrier();
  __builtin_amdgcn_sched_barrier(0);

  float trv[8];   // in-flight transpose column (registers; static indexing)

  for (int t = 0; t < NT; ++t) {
    const f16* bA = lds + (t % 3) * BUFSZ;
    const f16* bB = bA + BM * BK;
    const int tmod = t & 7;

    if (do_tr && tmod == 4) {    // store panel loaded at t-2 (drained by then)
      const int p = (flat << 3) | ((t - 4) >> 3);
      const int z = p >> 10, rem = p & 1023;
      const int koff = z ? D : 0;
      const int col = (rem & 31) * 64 + (tid & 63);
      const int k0 = (rem >> 5) * 64 + (tid >> 6) * 8;
      f16x8 h;
#pragma unroll
      for (int j = 0; j < 8; ++j) h[j] = (f16)trv[j];
      *(f16x8*)(BTn + (size_t)col * KT + koff + k0) = h;
    }
    if (do_tr && tmod == 2) {    // issue 8 f32 column loads for panel
      const int p = (flat << 3) | ((t - 2) >> 3);
      const int z = p >> 10, rem = p & 1023;
      const float* src = z ? nAu : nAl;
      const int col = (rem & 31) * 64 + (tid & 63);
      const int k0 = (rem >> 5) * 64 + (tid >> 6) * 8;
#pragma unroll
      for (int j = 0; j < 8; ++j)
        trv[j] = src[(size_t)(k0 + j) * D + col];
    }
    __builtin_amdgcn_sched_barrier(0);   // pin VMEM issue order vs stage

    if (t + 2 < NT) stage(t + 2, (t + 2) % 3);   // prefetch 2 tiles ahead
#pragma unroll
    for (int s = 0; s < 2; ++s) {
      const int ch = ((s * 4 + lq) ^ (lane & 7)) * 8;  // swizzled read chunk
      f16x8 af[4], bf[4];
#pragma unroll
      for (int m = 0; m < 4; ++m)
        af[m] = *(const f16x8*)(bA + (wm + m * 16 + lr) * BK + ch);
#pragma unroll
      for (int n = 0; n < 4; ++n)
        bf[n] = *(const f16x8*)(bB + (wn + n * 16 + lr) * BK + ch);
      __builtin_amdgcn_s_setprio(1);
#pragma unroll
      for (int m = 0; m < 4; ++m)
#pragma unroll
        for (int n = 0; n < 4; ++n)
          acc[m][n] = __builtin_amdgcn_mfma_f32_16x16x32_f16(
              bf[n], af[m], acc[m][n], 0, 0, 0);
      __builtin_amdgcn_s_setprio(0);
    }
    // counted wait: drain tile t+1's loads; keep t+2's (and tr loads) in flight
    if (t + 2 < NT) {
      if (do_tr && tmod == 2) {
        asm volatile("s_waitcnt vmcnt(14)" ::: "memory");  // +8 tr loads ride on
      } else {
        asm volatile("s_waitcnt vmcnt(6)" ::: "memory");
      }
    } else if (t + 1 < NT) {
      asm volatile("s_waitcnt vmcnt(0)" ::: "memory");
    }
    __builtin_amdgcn_sched_barrier(0);
    __builtin_amdgcn_s_barrier();
    __builtin_amdgcn_sched_barrier(0);
  }

  // ---- epilogue: sign-split store + fused bias contribution ----
  const int low = (m0 < D) ? 1 : 0;
  f32x4 w1v[4], w2v[4];
#pragma unroll
  for (int n = 0; n < 4; ++n) {
    const int col = n0 + wn + n * 16 + lq * 4;
    w1v[n] = *(const f32x4*)(w1 + col);
    w2v[n] = *(const f32x4*)(w2 + col);
  }
  float rowsum[4] = {0.f, 0.f, 0.f, 0.f};
#pragma unroll
  for (int m = 0; m < 4; ++m) {
#pragma unroll
    for (int n = 0; n < 4; ++n) {
      const size_t row = (size_t)(m0 + wm + m * 16 + lr);
      const int col = n0 + wn + n * 16 + lq * 4;
      f16x4 p, q;
#pragma unroll
      for (int r = 0; r < 4; ++r) {
        float v = acc[m][n][r];
        float pf2 = fmaxf(v, 0.f), qf = fminf(v, 0.f);
        p[r] = (f16)pf2;
        q[r] = (f16)qf;
        float wa = low ? w1v[n][r] : w2v[n][r];
        float wb = low ? w2v[n][r] : w1v[n][r];
        rowsum[m] += pf2 * wa + qf * wb;
      }
      if (wstate) {
        f16* base = An + row * KT + col;
        if (low) { *(f16x4*)base = p; *(f16x4*)(base + D) = q; }
        else     { *(f16x4*)base = q; *(f16x4*)(base + D) = p; }
      }
    }
  }
#pragma unroll
  for (int m = 0; m < 4; ++m) {
    float v = rowsum[m];
    v += __shfl_down(v, 32);
    v += __shfl_down(v, 16);
    if (lane < 16)
      atomicAdd(bdst + m0 + wm + m * 16 + lane, v);
  }
}

// ---- final: out[R] = outacc[R] + blbu[R] -----------------------------------
__global__ __launch_bounds__(256) void k_final(
    const float* __restrict__ outacc, const float* __restrict__ blbu,
    float* __restrict__ out) {
  const int R = blockIdx.x * 256 + threadIdx.x;
  out[R] = outacc[R] + blbu[R];
}

// ---- host ------------------------------------------------------------------
extern "C" void kernel_launch(void* const* d_in, const int* in_sizes, int n_in,
                              void* d_out, int out_size, void* d_ws, size_t ws_size,
                              hipStream_t stream) {
  (void)in_sizes; (void)n_in; (void)out_size;
  const float* A   = (const float*)d_in[0];
  const float* b   = (const float*)d_in[1];
  const float* hAl = (const float*)d_in[2];
  const float* hAu = (const float*)d_in[3];
  const float* hbl = (const float*)d_in[4];
  const float* hbu = (const float*)d_in[5];
  const float* lo  = (const float*)d_in[6];
  const float* up  = (const float*)d_in[7];
  float* out = (float*)d_out;

  const size_t AS = (size_t)2 * D * KT;     // Abig elems (f16)
  const size_t BS = (size_t)D * KT;         // Bb elems (f16)
  const size_t MS = (size_t)D * D;
  char* base = (char*)d_ws;
  f16* Ab0   = (f16*)base;
  f16* Ab1   = Ab0 + AS;
  f16* Bb0   = Ab1 + AS;
  float* blbu   = (float*)(Bb0 + BS);
  float* outacc = blbu + 2 * D;
  f16* Bb1   = (f16*)(outacc + 2 * D);
  const size_t need_fused = (size_t)((char*)(Bb1 + BS) - base);
  const bool fused = ws_size >= need_fused;

  k_init<<<dim3(D), 256, 0, stream>>>(
      A, b, hbl + (size_t)7 * D, hbu + (size_t)7 * D, Ab0, blbu, outacc);
  k_prep<<<dim3(2048), 512, 0, stream>>>(          // layer 7 -> Bb0
      hAl + (size_t)7 * MS, hAu + (size_t)7 * MS, Bb0);

  f16* cur = Ab0;
  f16* nxt = Ab1;
  for (int t = 0; t < L; ++t) {
    const int nlayer = 6 - t;   // layer for step t+1 (bias weights + transpose)
    const float* w1 = (t < 7) ? hbl + (size_t)nlayer * D : lo;
    const float* w2 = (t < 7) ? hbu + (size_t)nlayer * D : up;
    float* bd = (t < 7) ? blbu : outacc;
    f16* BT  = (fused && (t & 1)) ? Bb1 : Bb0;
    f16* BTn = fused ? ((t & 1) ? Bb0 : Bb1) : Bb0;
    const float* nl = (t < 7) ? hAl + (size_t)nlayer * MS : hAl;
    const float* nu = (t < 7) ? hAu + (size_t)nlayer * MS : hAu;
    if (!fused && t > 0)
      k_prep<<<dim3(2048), 512, 0, stream>>>(
          hAl + (size_t)(7 - t) * MS, hAu + (size_t)(7 - t) * MS, Bb0);
    const int do_tr = (fused && t < 7) ? 1 : 0;
    const int wstate = (t < 7) ? 1 : 0;
    k_gemm<<<dim3(256), 512, 0, stream>>>(cur, BT, BTn, nl, nu, w1, w2, bd,
                                          nxt, do_tr, wstate);
    f16* tmp = cur; cur = nxt; nxt = tmp;
  }
  k_final<<<dim3(2 * D / 256), 256, 0, stream>>>(outacc, blbu, out);
}